// Round 5
// baseline (8427.880 us; speedup 1.0000x reference)
//
#include <hip/hip_runtime.h>
#include <math.h>

constexpr int SEQ   = 256;
constexpr int BATCH = 512;
constexpr int INDIM = 300;
constexpr int KIH   = 320;        // INDIM zero-padded to 5*64
constexpr int HDIM  = 512;
constexpr int LDIM  = 256;
constexpr int G4    = 4 * HDIM;   // 2048

typedef _Float16 f16x8 __attribute__((ext_vector_type(8)));
typedef _Float16 f16x4 __attribute__((ext_vector_type(4)));
typedef float    f32x4 __attribute__((ext_vector_type(4)));

// ===========================================================================
// FAST PATH kernels
// ===========================================================================

// slab[by][64 rows (g*16+r)][832 cols: 0..319 Wih(pad), 320..831 Whh], linear
__global__ __launch_bounds__(256) void prep_weights_kernel(
    const float* __restrict__ Wih, const float* __restrict__ Whh,
    const float* __restrict__ bih, const float* __restrict__ bhh,
    _Float16* __restrict__ slab, float* __restrict__ bsum)
{
    const int by = blockIdx.x >> 6;
    const int rl = blockIdx.x & 63;
    const int g  = rl >> 4, r = rl & 15;
    const int grow = g * HDIM + by * 16 + r;
    const int tid = threadIdx.x;
    if (tid < 208) {
        const int col0 = tid * 4;
        f16x4 v;
        #pragma unroll
        for (int e = 0; e < 4; ++e) {
            const int col = col0 + e;
            float f;
            if (col < KIH) f = (col < INDIM) ? Wih[(size_t)grow * INDIM + col] : 0.f;
            else           f = Whh[(size_t)grow * HDIM + (col - KIH)];
            v[e] = (_Float16)f;
        }
        *(f16x4*)(slab + ((size_t)(by * 64 + rl)) * 832 + col0) = v;
    } else if (tid == 208) {
        bsum[grow] = bih[grow] + bhh[grow];
    }
}

// xall[t][b][320] fp16, LINEAR (zero-padded 300->320)
__global__ __launch_bounds__(256) void prep_x_kernel(
    const float* __restrict__ x, _Float16* __restrict__ xall)
{
    const int rowl = threadIdx.x >> 6;
    const int s    = threadIdx.x & 63;
    const int row  = blockIdx.x * 4 + rowl;   // t*512 + b, 0..131071
    if (s >= 40) return;
    const int k0 = s * 8;
    const float* xr = x + (size_t)row * INDIM;
    f16x8 v;
    #pragma unroll
    for (int e = 0; e < 8; ++e)
        v[e] = (k0 + e < INDIM) ? (_Float16)xr[k0 + e] : (_Float16)0.f;
    *(f16x8*)(xall + (size_t)row * KIH + k0) = v;
}

// Persistent LSTM: 256 blocks (8 bx x 32 by), 256 threads (4 waves).
// Block owns 64 batch x 16 hcols (x4 gates); weights (64x832 fp16) in VGPRs.
// PLAIN launch: grid=256 <= 256 CUs at 1 block/CU (launch_bounds 256,1;
// LDS 38.9KB) on a drained stream => all blocks co-resident by construction.
// Cross-block sync via agent-scope atomics (no coop-launch API needed).
__global__ __launch_bounds__(256, 1) void lstm_persist(
    const _Float16* __restrict__ xall,  // [SEQ][512][320] linear
    const _Float16* __restrict__ slab,  // [32][64][832] linear
    _Float16* __restrict__ hb,          // [2][512][512] linear ping-pong
    float* __restrict__ h32,            // [512][512] (written at t=SEQ-1)
    const float* __restrict__ bsum,     // [2048]
    int* __restrict__ cnt)              // [SEQ][8]
{
    // 160B row stride => row*160 ≡ 8*row banks (mod 32): 2-way max conflicts
    __shared__ _Float16 ring[2][64][80];  // 20 KB, two chunk slots
    __shared__ float    Gb[4][64][18];    // 18.4 KB gate exchange

    const int tid  = threadIdx.x;
    const int wid  = tid >> 6;
    const int lane = tid & 63;
    const int bx   = blockIdx.x >> 5;
    const int by   = blockIdx.x & 31;
    const int b0   = bx * 64;
    const int hc0  = by * 16;
    const int gh   = wid >> 1;   // gate-row half (0..1)
    const int bh   = wid & 1;    // batch half (0..1)
    const int l15  = lane & 15;
    const int q4   = lane >> 4;

    // ---- weights -> registers: 52 x f16x8 (208 VGPR), all-static indexing ----
    f16x8 wreg[13][2][2];
    {
        const _Float16* sb = slab + (size_t)by * 64 * 832;
        #pragma unroll
        for (int chv = 0; chv < 13; ++chv)
            #pragma unroll
            for (int kl = 0; kl < 2; ++kl)
                #pragma unroll
                for (int mt = 0; mt < 2; ++mt) {
                    const int rrow = gh * 32 + mt * 16 + l15;
                    const int kk   = chv * 64 + kl * 32 + q4 * 8;
                    wreg[chv][kl][mt] = *(const f16x8*)(sb + (size_t)rrow * 832 + kk);
                }
    }

    // ---- staging lane constants: 2 ops/thread, 16B each, rows linear ----
    int srow[2], suu[2], woff[2];
    #pragma unroll
    for (int ii = 0; ii < 2; ++ii) {
        const int lin = ((wid * 2 + ii) << 10) + (lane << 4);  // byte in 8KB chunk
        srow[ii] = lin >> 7;            // 0..63
        suu[ii]  = (lin >> 4) & 7;      // 0..7 (16B unit)
        woff[ii] = srow[ii] * 160 + suu[ii] * 16;  // padded LDS byte offset
    }

    // ---- B-fragment read offsets (padded rows, no swizzle) ----
    const int roffA = (bh * 32 + l15) * 160 + q4 * 16;       // nt=0
    const int roffB = roffA + 16 * 160;                      // nt=1

    // ---- cell-update constants ----
    const int bl  = tid >> 2;          // 0..63 local batch
    const int j0l = (tid & 3) << 2;    // 0,4,8,12 local hcol
    const int bg  = b0 + bl;
    const int jg  = hc0 + j0l;
    const f32x4 bi  = *(const f32x4*)&bsum[0 * HDIM + jg];
    const f32x4 bf  = *(const f32x4*)&bsum[1 * HDIM + jg];
    const f32x4 bgi = *(const f32x4*)&bsum[2 * HDIM + jg];
    const f32x4 bo  = *(const f32x4*)&bsum[3 * HDIM + jg];
    f32x4 cv = {0.f, 0.f, 0.f, 0.f};

    f16x8 rbuf[2][2];

#define BAR() do { asm volatile("" ::: "memory");                            \
                   __builtin_amdgcn_s_barrier();                             \
                   asm volatile("" ::: "memory"); } while (0)

#define LOADX(CH) do {                                                       \
        _Pragma("unroll")                                                    \
        for (int ii = 0; ii < 2; ++ii)                                       \
            rbuf[(CH) & 1][ii] = *(const f16x8*)(xrow0 +                     \
                (size_t)srow[ii] * KIH + (((CH) * 8 + suu[ii]) << 3));       \
    } while (0)

#define LOADH(CH) do {                                                       \
        _Pragma("unroll")                                                    \
        for (int ii = 0; ii < 2; ++ii) {                                     \
            const unsigned long long* _p = (const unsigned long long*)       \
                (hrow0 + (size_t)srow[ii] * HDIM +                           \
                 ((((CH) - 5) * 8 + suu[ii]) << 3));                         \
            union { unsigned long long u[2]; f16x8 v; } _t;                  \
            _t.u[0] = __hip_atomic_load(_p,     __ATOMIC_RELAXED,            \
                                        __HIP_MEMORY_SCOPE_AGENT);           \
            _t.u[1] = __hip_atomic_load(_p + 1, __ATOMIC_RELAXED,            \
                                        __HIP_MEMORY_SCOPE_AGENT);           \
            rbuf[(CH) & 1][ii] = _t.v;                                       \
        }                                                                    \
    } while (0)

#define LOADR(CH) do { if ((CH) < 5) LOADX(CH); else LOADH(CH); } while (0)

#define CCHUNK(I) do {                                                       \
        const char* _c = (const char*)&ring[(I) & 1][0][0];                  \
        _Pragma("unroll")                                                    \
        for (int kl = 0; kl < 2; ++kl) {                                     \
            const f16x8 b0f = *(const f16x8*)(_c + roffA + kl * 64);         \
            const f16x8 b1f = *(const f16x8*)(_c + roffB + kl * 64);         \
            acc00 = __builtin_amdgcn_mfma_f32_16x16x32_f16(wreg[I][kl][0], b0f, acc00, 0, 0, 0); \
            acc01 = __builtin_amdgcn_mfma_f32_16x16x32_f16(wreg[I][kl][0], b1f, acc01, 0, 0, 0); \
            acc10 = __builtin_amdgcn_mfma_f32_16x16x32_f16(wreg[I][kl][1], b0f, acc10, 0, 0, 0); \
            acc11 = __builtin_amdgcn_mfma_f32_16x16x32_f16(wreg[I][kl][1], b1f, acc11, 0, 0, 0); \
        }                                                                    \
    } while (0)

#define SCHUNK(I) do {                                                       \
        BAR();  /* ring slot (I)&1 free: chunk I-2 readers drained their DS  \
                   ops at SCHUNK(I-1)'s lgkmcnt(0)+barrier */                \
        {                                                                    \
            char* _w = (char*)&ring[(I) & 1][0][0];                          \
            _Pragma("unroll")                                                \
            for (int ii = 0; ii < 2; ++ii)                                   \
                *(f16x8*)(_w + woff[ii]) = rbuf[(I) & 1][ii];                \
        }                                                                    \
        if ((I) == 3) {  /* producers of h[t] must be done before h loads */ \
            if (t > 0 && tid == 0) {                                         \
                int _wd = 0;                                                 \
                while (__hip_atomic_load(&cnt[(t - 1) * 8 + bx],             \
                        __ATOMIC_ACQUIRE, __HIP_MEMORY_SCOPE_AGENT) < 32     \
                       && _wd < (1 << 16)) {                                 \
                    __builtin_amdgcn_s_sleep(8); ++_wd;                      \
                }                                                            \
            }                                                                \
            BAR();                                                           \
        }                                                                    \
        if ((I) + 2 <= 12) LOADR((I) + 2);                                   \
        asm volatile("s_waitcnt lgkmcnt(0)" ::: "memory");  /* ds_writes done */ \
        BAR();                                                               \
        CCHUNK(I);                                                           \
    } while (0)

    for (int t = 0; t < SEQ; ++t) {
        const _Float16* xrow0 = xall + ((size_t)t * BATCH + b0) * KIH;
        const _Float16* hrow0 = hb + (size_t)(t & 1) * BATCH * HDIM + (size_t)b0 * HDIM;
        _Float16* hbw = hb + (size_t)((t + 1) & 1) * BATCH * HDIM;

        f32x4 acc00 = {0,0,0,0}, acc01 = {0,0,0,0}, acc10 = {0,0,0,0}, acc11 = {0,0,0,0};

        LOADR(0); LOADR(1);
        SCHUNK(0); SCHUNK(1); SCHUNK(2); SCHUNK(3); SCHUNK(4);
        SCHUNK(5); SCHUNK(6); SCHUNK(7); SCHUNK(8); SCHUNK(9);
        SCHUNK(10); SCHUNK(11); SCHUNK(12);

        // ---- gate preactivations -> LDS (disjoint per wave) ----
        {
            const int rb = q4 * 4;
            #pragma unroll
            for (int q = 0; q < 4; ++q) {
                Gb[gh * 2 + 0][bh * 32 + 0 * 16 + l15][rb + q] = acc00[q];
                Gb[gh * 2 + 0][bh * 32 + 1 * 16 + l15][rb + q] = acc01[q];
                Gb[gh * 2 + 1][bh * 32 + 0 * 16 + l15][rb + q] = acc10[q];
                Gb[gh * 2 + 1][bh * 32 + 1 * 16 + l15][rb + q] = acc11[q];
            }
        }
        asm volatile("s_waitcnt lgkmcnt(0)" ::: "memory");
        BAR();

        // ---- LSTM cell update (c in registers) ----
        {
            f32x4 hv;
            #pragma unroll
            for (int q = 0; q < 4; ++q) {
                float vi = Gb[0][bl][j0l + q] + bi[q];
                float vf = Gb[1][bl][j0l + q] + bf[q];
                float vg = Gb[2][bl][j0l + q] + bgi[q];
                float vo = Gb[3][bl][j0l + q] + bo[q];
                vi = 1.f / (1.f + __expf(-vi));
                vf = 1.f / (1.f + __expf(-vf));
                vg = tanhf(vg);
                vo = 1.f / (1.f + __expf(-vo));
                const float cc = vf * cv[q] + vi * vg;
                cv[q] = cc;
                hv[q] = vo * tanhf(cc);
            }
            union { unsigned long long u; f16x4 v; } hu;
            hu.v[0] = (_Float16)hv[0]; hu.v[1] = (_Float16)hv[1];
            hu.v[2] = (_Float16)hv[2]; hu.v[3] = (_Float16)hv[3];
            __hip_atomic_store((unsigned long long*)(hbw + (size_t)bg * HDIM + jg),
                               hu.u, __ATOMIC_RELAXED, __HIP_MEMORY_SCOPE_AGENT);
            if (t == SEQ - 1)
                *(f32x4*)(h32 + (size_t)bg * HDIM + jg) = hv;
        }
        __threadfence();
        BAR();
        if (tid == 0)
            __hip_atomic_fetch_add(&cnt[t * 8 + bx], 1,
                                   __ATOMIC_RELEASE, __HIP_MEMORY_SCOPE_AGENT);
    }
#undef BAR
#undef LOADX
#undef LOADH
#undef LOADR
#undef CCHUNK
#undef SCHUNK
}

// ===========================================================================
// FALLBACK PATH (round-2, known-good) kernels
// ===========================================================================
__global__ __launch_bounds__(256) void prep_kernel(
    const float* __restrict__ Wih, const float* __restrict__ Whh,
    const float* __restrict__ bih, const float* __restrict__ bhh,
    _Float16* __restrict__ Wihc, _Float16* __restrict__ Whhc,
    float* __restrict__ bsum)
{
    const int g = blockIdx.x;
    for (int col = threadIdx.x; col < KIH; col += 256)
        Wihc[(size_t)g * KIH + col] =
            (col < INDIM) ? (_Float16)Wih[(size_t)g * INDIM + col] : (_Float16)0.f;
    for (int col = threadIdx.x; col < HDIM; col += 256)
        Whhc[(size_t)g * HDIM + col] = (_Float16)Whh[(size_t)g * HDIM + col];
    if (threadIdx.x == 0) bsum[g] = bih[g] + bhh[g];
}

__global__ __launch_bounds__(256) void fused_step_kernel(
    const float* __restrict__ xt, const _Float16* __restrict__ Wihc,
    const _Float16* __restrict__ Whhc, const float* __restrict__ bsum,
    float* __restrict__ c, float* __restrict__ h)
{
    __shared__ _Float16 As[32][72];
    __shared__ _Float16 Bs[128][72];
    __shared__ float    Gb[4][32][36];

    const int tid = threadIdx.x;
    const int b0  = blockIdx.x * 32;
    const int hc0 = blockIdx.y * 32;
    const int wid  = tid >> 6;
    const int lane = tid & 63;

    f32x4 acc[2][2] = {};
    const int arow = tid >> 3;
    const int ac8  = (tid & 7) * 8;
    const int brr  = tid >> 1;
    const int bseg = (tid & 1) * 32;

    for (int phase = 0; phase < 2; ++phase) {
        const float* Asrc = phase ? h : xt;
        const _Float16* Bsrc = phase ? Whhc : Wihc;
        const int Kpad = phase ? HDIM : KIH;
        const int Kval = phase ? HDIM : INDIM;
        const int astr = phase ? HDIM : INDIM;

        for (int k0 = 0; k0 < Kpad; k0 += 64) {
            const int gk = k0 + ac8;
            const float* pa = Asrc + (size_t)(b0 + arow) * astr + gk;
            float4 u = {0.f,0.f,0.f,0.f}, v = {0.f,0.f,0.f,0.f};
            if (gk + 3 < Kval)  u = *(const float4*)pa;
            if (gk + 7 < Kval)  v = *(const float4*)(pa + 4);
            f16x8 a8;
            a8[0]=(_Float16)u.x; a8[1]=(_Float16)u.y; a8[2]=(_Float16)u.z; a8[3]=(_Float16)u.w;
            a8[4]=(_Float16)v.x; a8[5]=(_Float16)v.y; a8[6]=(_Float16)v.z; a8[7]=(_Float16)v.w;
            const int grow = (brr >> 5) * HDIM + hc0 + (brr & 31);
            const _Float16* pb = Bsrc + (size_t)grow * Kpad + k0 + bseg;
            f16x8 w0 = *(const f16x8*)(pb + 0);
            f16x8 w1 = *(const f16x8*)(pb + 8);
            f16x8 w2 = *(const f16x8*)(pb + 16);
            f16x8 w3 = *(const f16x8*)(pb + 24);
            __syncthreads();
            *(f16x8*)&As[arow][ac8] = a8;
            *(f16x8*)&Bs[brr][bseg + 0]  = w0;
            *(f16x8*)&Bs[brr][bseg + 8]  = w1;
            *(f16x8*)&Bs[brr][bseg + 16] = w2;
            *(f16x8*)&Bs[brr][bseg + 24] = w3;
            __syncthreads();
            const int lr = lane & 15;
            const int lk = (lane >> 4) * 8;
            #pragma unroll
            for (int kf = 0; kf < 2; ++kf) {
                const int kl = kf * 32 + lk;
                f16x8 a0 = *(const f16x8*)&As[lr][kl];
                f16x8 a1 = *(const f16x8*)&As[16 + lr][kl];
                f16x8 bb0 = *(const f16x8*)&Bs[wid * 32 + lr][kl];
                f16x8 bb1 = *(const f16x8*)&Bs[wid * 32 + 16 + lr][kl];
                acc[0][0] = __builtin_amdgcn_mfma_f32_16x16x32_f16(a0, bb0, acc[0][0], 0, 0, 0);
                acc[0][1] = __builtin_amdgcn_mfma_f32_16x16x32_f16(a0, bb1, acc[0][1], 0, 0, 0);
                acc[1][0] = __builtin_amdgcn_mfma_f32_16x16x32_f16(a1, bb0, acc[1][0], 0, 0, 0);
                acc[1][1] = __builtin_amdgcn_mfma_f32_16x16x32_f16(a1, bb1, acc[1][1], 0, 0, 0);
            }
        }
    }
    __syncthreads();
    {
        const int cn = lane & 15;
        const int rb = (lane >> 4) * 4;
        #pragma unroll
        for (int mi = 0; mi < 2; ++mi)
            #pragma unroll
            for (int ni = 0; ni < 2; ++ni)
                #pragma unroll
                for (int r = 0; r < 4; ++r)
                    Gb[wid][mi * 16 + rb + r][ni * 16 + cn] = acc[mi][ni][r];
    }
    __syncthreads();
    {
        const int bl  = tid >> 3;
        const int jl0 = (tid & 7) * 4;
        const int gb  = b0 + bl;
        const int gj  = hc0 + jl0;
        const f32x4 ig = *(const f32x4*)&Gb[0][bl][jl0];
        const f32x4 fg = *(const f32x4*)&Gb[1][bl][jl0];
        const f32x4 gg = *(const f32x4*)&Gb[2][bl][jl0];
        const f32x4 og = *(const f32x4*)&Gb[3][bl][jl0];
        const f32x4 bi = *(const f32x4*)&bsum[0 * HDIM + gj];
        const f32x4 bf = *(const f32x4*)&bsum[1 * HDIM + gj];
        const f32x4 bg = *(const f32x4*)&bsum[2 * HDIM + gj];
        const f32x4 bo = *(const f32x4*)&bsum[3 * HDIM + gj];
        float* cp = c + (size_t)gb * HDIM + gj;
        float* hp = h + (size_t)gb * HDIM + gj;
        f32x4 cvv = *(const f32x4*)cp;
        f32x4 hv;
        #pragma unroll
        for (int q = 0; q < 4; ++q) {
            const float iv = 1.f / (1.f + __expf(-(ig[q] + bi[q])));
            const float fv = 1.f / (1.f + __expf(-(fg[q] + bf[q])));
            const float gv = tanhf(gg[q] + bg[q]);
            const float ov = 1.f / (1.f + __expf(-(og[q] + bo[q])));
            const float cc = fv * cvv[q] + iv * gv;
            cvv[q] = cc;
            hv[q] = ov * tanhf(cc);
        }
        *(f32x4*)cp = cvv;
        *(f32x4*)hp = hv;
    }
}

// ===========================================================================
// Shared epilogue
// ===========================================================================
__global__ __launch_bounds__(256) void bn_stats_kernel(
    const float* __restrict__ X, int nfeat,
    const float* __restrict__ gamma, const float* __restrict__ beta,
    float* __restrict__ s, float* __restrict__ t)
{
    const int f = blockIdx.x * 256 + threadIdx.x;
    if (f >= nfeat) return;
    float sum = 0.f, sq = 0.f;
    for (int b = 0; b < BATCH; ++b) {
        const float v = X[(size_t)b * nfeat + f];
        sum += v; sq += v * v;
    }
    const float mean = sum * (1.f / BATCH);
    const float var  = sq * (1.f / BATCH) - mean * mean;
    const float rstd = rsqrtf(var + 1e-5f);
    const float sc   = gamma[f] * rstd;
    s[f] = sc;
    t[f] = beta[f] - mean * sc;
}

__global__ __launch_bounds__(256) void fc1_kernel(
    const float* __restrict__ h, const float* __restrict__ s1,
    const float* __restrict__ t1, const float* __restrict__ W1,
    const float* __restrict__ b1, float* __restrict__ out1)
{
    const int b = blockIdx.x;
    const int l = threadIdx.x;
    const float* hb = h  + (size_t)b * HDIM;
    const float* wl = W1 + (size_t)l * HDIM;
    float acc = 0.f;
    for (int k = 0; k < HDIM; ++k)
        acc += (hb[k] * s1[k] + t1[k]) * wl[k];
    out1[(size_t)b * LDIM + l] = acc + b1[l];
}

__global__ __launch_bounds__(256) void final_kernel(
    const float* __restrict__ out1, const float* __restrict__ s2,
    const float* __restrict__ t2, const float* __restrict__ W2,
    const float* __restrict__ b2, float* __restrict__ out)
{
    const int b = blockIdx.x;
    float v = out1[(size_t)b * LDIM + threadIdx.x];
    v = v * s2[threadIdx.x] + t2[threadIdx.x];
    v = fmaxf(v, 0.f);
    v *= W2[threadIdx.x];
    #pragma unroll
    for (int off = 32; off > 0; off >>= 1) v += __shfl_down(v, off);
    __shared__ float red[4];
    if ((threadIdx.x & 63) == 0) red[threadIdx.x >> 6] = v;
    __syncthreads();
    if (threadIdx.x == 0) {
        const float ssum = red[0] + red[1] + red[2] + red[3] + b2[0];
        out[b] = 4.f / (1.f + expf(-ssum));
    }
}

// ===========================================================================
extern "C" void kernel_launch(void* const* d_in, const int* in_sizes, int n_in,
                              void* d_out, int out_size, void* d_ws, size_t ws_size,
                              hipStream_t stream) {
    const float* x   = (const float*)d_in[0];
    const float* Wih = (const float*)d_in[1];
    const float* Whh = (const float*)d_in[2];
    const float* bih = (const float*)d_in[3];
    const float* bhh = (const float*)d_in[4];
    const float* g1  = (const float*)d_in[5];
    const float* be1 = (const float*)d_in[6];
    const float* W1  = (const float*)d_in[7];
    const float* b1  = (const float*)d_in[8];
    const float* g2  = (const float*)d_in[9];
    const float* be2 = (const float*)d_in[10];
    const float* W2  = (const float*)d_in[11];
    const float* b2  = (const float*)d_in[12];
    float* out = (float*)d_out;

    // ---- fast-path workspace layout ----
    const size_t SZ_XALL = (size_t)SEQ * BATCH * KIH * 2;       // 83,886,080
    const size_t SZ_SLAB = (size_t)32 * 64 * 832 * 2;           //  3,407,872
    const size_t SZ_HB   = (size_t)2 * BATCH * HDIM * 2;        //  1,048,576
    const size_t SZ_H32  = (size_t)BATCH * HDIM * 4;            //  1,048,576
    const size_t SZ_BSUM = (size_t)G4 * 4;
    const size_t SZ_CNT  = (size_t)SEQ * 8 * 4;
    const size_t SZ_ST   = (size_t)(HDIM * 2 + LDIM * 2) * 4;
    const size_t SZ_OUT1 = (size_t)BATCH * LDIM * 4;
    const size_t NEED = SZ_XALL + SZ_SLAB + SZ_HB + SZ_H32 + SZ_BSUM +
                        SZ_CNT + SZ_ST + SZ_OUT1;

    if (ws_size >= NEED) {
        char* p = (char*)d_ws;
        _Float16* xall = (_Float16*)p;           p += SZ_XALL;
        _Float16* slab = (_Float16*)p;           p += SZ_SLAB;
        _Float16* hbuf = (_Float16*)p;           p += SZ_HB;
        float* h32     = (float*)p;              p += SZ_H32;
        float* bsum    = (float*)p;              p += SZ_BSUM;
        int*   cnt     = (int*)p;                p += SZ_CNT;
        float* s1 = (float*)p;                   p += HDIM * 4;
        float* t1 = (float*)p;                   p += HDIM * 4;
        float* s2 = (float*)p;                   p += LDIM * 4;
        float* t2 = (float*)p;                   p += LDIM * 4;
        float* out1 = (float*)p;

        hipMemsetAsync(hbuf, 0, SZ_HB, stream);
        hipMemsetAsync(cnt, 0, SZ_CNT, stream);
        prep_weights_kernel<<<2048, 256, 0, stream>>>(Wih, Whh, bih, bhh, slab, bsum);
        prep_x_kernel<<<SEQ * 128, 256, 0, stream>>>(x, xall);

        // PLAIN launch (no coop API): 256 blocks on 256 CUs, co-resident by
        // construction; cross-block sync is homemade agent-scope atomics.
        lstm_persist<<<dim3(256), dim3(256), 0, stream>>>(
            xall, slab, hbuf, h32, bsum, cnt);

        bn_stats_kernel<<<2, 256, 0, stream>>>(h32, HDIM, g1, be1, s1, t1);
        fc1_kernel<<<BATCH, 256, 0, stream>>>(h32, s1, t1, W1, b1, out1);
        bn_stats_kernel<<<1, 256, 0, stream>>>(out1, LDIM, g2, be2, s2, t2);
        final_kernel<<<BATCH, 256, 0, stream>>>(out1, s2, t2, W2, b2, out);
    } else {
        // ---- fallback: round-2 path ----
        float* ws   = (float*)d_ws;
        float* h    = ws;
        float* c    = h + BATCH * HDIM;
        float* bsum = c + BATCH * HDIM;
        float* s1   = bsum + G4;
        float* t1   = s1 + HDIM;
        float* s2   = t1 + HDIM;
        float* t2   = s2 + LDIM;
        float* out1 = t2 + LDIM;
        _Float16* Wihc = (_Float16*)(out1 + (size_t)BATCH * LDIM);
        _Float16* Whhc = Wihc + (size_t)G4 * KIH;

        hipMemsetAsync(h, 0, (size_t)2 * BATCH * HDIM * sizeof(float), stream);
        prep_kernel<<<G4, 256, 0, stream>>>(Wih, Whh, bih, bhh, Wihc, Whhc, bsum);
        const dim3 sgrid(BATCH / 32, HDIM / 32);
        for (int t = 0; t < SEQ; ++t) {
            fused_step_kernel<<<sgrid, 256, 0, stream>>>(
                x + (size_t)t * BATCH * INDIM, Wihc, Whhc, bsum, c, h);
        }
        bn_stats_kernel<<<2, 256, 0, stream>>>(h, HDIM, g1, be1, s1, t1);
        fc1_kernel<<<BATCH, 256, 0, stream>>>(h, s1, t1, W1, b1, out1);
        bn_stats_kernel<<<1, 256, 0, stream>>>(out1, LDIM, g2, be2, s2, t2);
        final_kernel<<<BATCH, 256, 0, stream>>>(out1, s2, t2, W2, b2, out);
    }
}

// Round 6
// 1346.560 us; speedup vs baseline: 6.2588x; 6.2588x over previous
//
#include <hip/hip_runtime.h>
#include <math.h>

constexpr int SEQ   = 256;
constexpr int BATCH = 512;
constexpr int INDIM = 300;
constexpr int KIH   = 320;        // INDIM zero-padded to 5*64
constexpr int HDIM  = 512;
constexpr int LDIM  = 256;
constexpr int G4    = 4 * HDIM;   // 2048

typedef _Float16 f16x8 __attribute__((ext_vector_type(8)));
typedef _Float16 f16x4 __attribute__((ext_vector_type(4)));
typedef float    f32x4 __attribute__((ext_vector_type(4)));

// ===========================================================================
// FAST PATH kernels
// ===========================================================================

// slab[by][64 rows (g*16+r)][832 cols: 0..319 Wih(pad), 320..831 Whh], linear
__global__ __launch_bounds__(256) void prep_weights_kernel(
    const float* __restrict__ Wih, const float* __restrict__ Whh,
    const float* __restrict__ bih, const float* __restrict__ bhh,
    _Float16* __restrict__ slab, float* __restrict__ bsum)
{
    const int by = blockIdx.x >> 6;
    const int rl = blockIdx.x & 63;
    const int g  = rl >> 4, r = rl & 15;
    const int grow = g * HDIM + by * 16 + r;
    const int tid = threadIdx.x;
    if (tid < 208) {
        const int col0 = tid * 4;
        f16x4 v;
        #pragma unroll
        for (int e = 0; e < 4; ++e) {
            const int col = col0 + e;
            float f;
            if (col < KIH) f = (col < INDIM) ? Wih[(size_t)grow * INDIM + col] : 0.f;
            else           f = Whh[(size_t)grow * HDIM + (col - KIH)];
            v[e] = (_Float16)f;
        }
        *(f16x4*)(slab + ((size_t)(by * 64 + rl)) * 832 + col0) = v;
    } else if (tid == 208) {
        bsum[grow] = bih[grow] + bhh[grow];
    }
}

// xall[t][b][320] fp16, LINEAR (zero-padded 300->320)
__global__ __launch_bounds__(256) void prep_x_kernel(
    const float* __restrict__ x, _Float16* __restrict__ xall)
{
    const int rowl = threadIdx.x >> 6;
    const int s    = threadIdx.x & 63;
    const int row  = blockIdx.x * 4 + rowl;   // t*512 + b
    if (s >= 40) return;
    const int k0 = s * 8;
    const float* xr = x + (size_t)row * INDIM;
    f16x8 v;
    #pragma unroll
    for (int e = 0; e < 8; ++e)
        v[e] = (k0 + e < INDIM) ? (_Float16)xr[k0 + e] : (_Float16)0.f;
    *(f16x8*)(xall + (size_t)row * KIH + k0) = v;
}

// Persistent LSTM: 256 blocks, 256 threads (4 waves), 1 block/CU.
// bx = bid&7 (== XCD id) so each producer/consumer group (same bx) is
// XCD-local; by = bid>>3. Block owns 64 batch x 16 hcols; W in VGPRs.
// Sync: per-block flag store (no RMW), lane-parallel relaxed poll.
__global__ __launch_bounds__(256, 1) void lstm_persist(
    const _Float16* __restrict__ xall,  // [SEQ][512][320] linear
    const _Float16* __restrict__ slab,  // [32][64][832] linear
    _Float16* __restrict__ hb,          // [2][512][512] linear ping-pong
    float* __restrict__ h32,            // [512][512] (written at t=SEQ-1)
    const float* __restrict__ bsum,     // [2048]
    int* __restrict__ cnt)              // flags[8][32]
{
    // 176B row stride: ds_read_b128 B-frags max 2-way bank aliased (free)
    __shared__ _Float16 ring[2][64][88];  // 22.0 KB
    __shared__ float    Gb[4][64][18];    // 18.4 KB

    const int tid  = threadIdx.x;
    const int wid  = tid >> 6;
    const int lane = tid & 63;
    const int bx   = blockIdx.x & 7;    // XCD-aligned group id
    const int by   = blockIdx.x >> 3;   // 0..31
    const int b0   = bx * 64;
    const int hc0  = by * 16;
    const int gh   = wid >> 1;
    const int bh   = wid & 1;
    const int l15  = lane & 15;
    const int q4   = lane >> 4;

    // ---- weights -> registers: 52 x f16x8, all-static indexing ----
    f16x8 wreg[13][2][2];
    {
        const _Float16* sb = slab + (size_t)by * 64 * 832;
        #pragma unroll
        for (int chv = 0; chv < 13; ++chv)
            #pragma unroll
            for (int kl = 0; kl < 2; ++kl)
                #pragma unroll
                for (int mt = 0; mt < 2; ++mt) {
                    const int rrow = gh * 32 + mt * 16 + l15;
                    const int kk   = chv * 64 + kl * 32 + q4 * 8;
                    wreg[chv][kl][mt] = *(const f16x8*)(sb + (size_t)rrow * 832 + kk);
                }
    }

    // ---- staging lane constants ----
    int srow[2], suu[2], woff[2];
    #pragma unroll
    for (int ii = 0; ii < 2; ++ii) {
        const int lin = ((wid * 2 + ii) << 10) + (lane << 4);
        srow[ii] = lin >> 7;
        suu[ii]  = (lin >> 4) & 7;
        woff[ii] = srow[ii] * 176 + suu[ii] * 16;
    }
    const int roffA = (bh * 32 + l15) * 176 + q4 * 16;
    const int roffB = roffA + 16 * 176;

    // ---- cell-update constants ----
    const int bl  = tid >> 2;
    const int j0l = (tid & 3) << 2;
    const int bg  = b0 + bl;
    const int jg  = hc0 + j0l;
    const f32x4 bi  = *(const f32x4*)&bsum[0 * HDIM + jg];
    const f32x4 bf  = *(const f32x4*)&bsum[1 * HDIM + jg];
    const f32x4 bgi = *(const f32x4*)&bsum[2 * HDIM + jg];
    const f32x4 bo  = *(const f32x4*)&bsum[3 * HDIM + jg];
    f32x4 cv = {0.f, 0.f, 0.f, 0.f};

    f16x8 rb[4][2];   // 4-slot register ring, 3-chunk lookahead

#define BARX() do { asm volatile("" ::: "memory");                           \
                    __builtin_amdgcn_s_barrier();                            \
                    asm volatile("" ::: "memory"); } while (0)

// chunk J (step-local, 0..16): 0..4 x@xrow0, 5..12 h@hrow0, 13..16 x@xrow1
#define LOADC(J, P) do {                                                     \
    _Pragma("unroll")                                                        \
    for (int ii = 0; ii < 2; ++ii) {                                         \
        if ((J) < 5) {                                                       \
            rb[((P)+(J)) & 3][ii] = *(const f16x8*)(xrow0 +                  \
                (size_t)srow[ii] * KIH + (((J) * 8 + suu[ii]) << 3));        \
        } else if ((J) < 13) {                                               \
            const unsigned long long* _p = (const unsigned long long*)       \
                (hrow0 + (size_t)srow[ii] * HDIM +                           \
                 ((((J) - 5) * 8 + suu[ii]) << 3));                          \
            union { unsigned long long u[2]; f16x8 v; } _t;                  \
            _t.u[0] = __hip_atomic_load(_p,     __ATOMIC_RELAXED,            \
                                        __HIP_MEMORY_SCOPE_AGENT);          \
            _t.u[1] = __hip_atomic_load(_p + 1, __ATOMIC_RELAXED,           \
                                        __HIP_MEMORY_SCOPE_AGENT);          \
            rb[((P)+(J)) & 3][ii] = _t.v;                                    \
        } else {                                                             \
            rb[((P)+(J)) & 3][ii] = *(const f16x8*)(xrow1 +                  \
                (size_t)srow[ii] * KIH + ((((J) - 13) * 8 + suu[ii]) << 3)); \
        }                                                                    \
    }                                                                        \
} while (0)

// One pipeline iteration: poll (I==1), prefetch I+4, write I+1, compute I.
#define ITER(I, P, TT) do {                                                  \
    if ((I) == 1 && (TT) > 0) {                                              \
        const int* _fp = cnt + bx * 32 + (lane & 31);                        \
        int _wd = 0;                                                         \
        for (;;) {                                                           \
            const int _f = __hip_atomic_load(_fp, __ATOMIC_RELAXED,          \
                                             __HIP_MEMORY_SCOPE_AGENT);     \
            if (__all(_f >= (TT))) break;                                    \
            if (++_wd > (1 << 20)) break;                                    \
            __builtin_amdgcn_s_sleep(1);                                     \
        }                                                                    \
    }                                                                        \
    LOADC((I) + 4, P);                                                       \
    {                                                                        \
        char* _w = (char*)&ring[((P)+(I)+1) & 1][0][0];                      \
        _Pragma("unroll")                                                    \
        for (int ii = 0; ii < 2; ++ii)                                       \
            *(f16x8*)(_w + woff[ii]) = rb[((P)+(I)+1) & 3][ii];              \
    }                                                                        \
    {                                                                        \
        const char* _c = (const char*)&ring[((P)+(I)) & 1][0][0];            \
        _Pragma("unroll")                                                    \
        for (int kl = 0; kl < 2; ++kl) {                                     \
            const f16x8 b0f = *(const f16x8*)(_c + roffA + kl * 64);         \
            const f16x8 b1f = *(const f16x8*)(_c + roffB + kl * 64);         \
            acc00 = __builtin_amdgcn_mfma_f32_16x16x32_f16(wreg[I][kl][0], b0f, acc00, 0, 0, 0); \
            acc01 = __builtin_amdgcn_mfma_f32_16x16x32_f16(wreg[I][kl][0], b1f, acc01, 0, 0, 0); \
            acc10 = __builtin_amdgcn_mfma_f32_16x16x32_f16(wreg[I][kl][1], b0f, acc10, 0, 0, 0); \
            acc11 = __builtin_amdgcn_mfma_f32_16x16x32_f16(wreg[I][kl][1], b1f, acc11, 0, 0, 0); \
        }                                                                    \
    }                                                                        \
    asm volatile("s_waitcnt lgkmcnt(0)" ::: "memory");                       \
    BARX();                                                                  \
} while (0)

#define STEP(TT, P) do {                                                     \
    const _Float16* xrow0 = xall + ((size_t)(TT) * BATCH + b0) * KIH;        \
    const _Float16* xrow1 = xrow0 + (size_t)BATCH * KIH;                     \
    const _Float16* hrow0 = hb + (size_t)((P) & 1) * BATCH * HDIM            \
                               + (size_t)b0 * HDIM;                          \
    f32x4 acc00 = {0,0,0,0}, acc01 = {0,0,0,0},                              \
          acc10 = {0,0,0,0}, acc11 = {0,0,0,0};                              \
    ITER(0,P,TT); ITER(1,P,TT); ITER(2,P,TT); ITER(3,P,TT); ITER(4,P,TT);    \
    ITER(5,P,TT); ITER(6,P,TT); ITER(7,P,TT); ITER(8,P,TT); ITER(9,P,TT);    \
    ITER(10,P,TT); ITER(11,P,TT); ITER(12,P,TT);                             \
    {   /* gates -> Gb (disjoint per wave) */                                \
        const int rbq = q4 * 4;                                              \
        _Pragma("unroll")                                                    \
        for (int q = 0; q < 4; ++q) {                                        \
            Gb[gh*2+0][bh*32 +      l15][rbq+q] = acc00[q];                  \
            Gb[gh*2+0][bh*32 + 16 + l15][rbq+q] = acc01[q];                  \
            Gb[gh*2+1][bh*32 +      l15][rbq+q] = acc10[q];                  \
            Gb[gh*2+1][bh*32 + 16 + l15][rbq+q] = acc11[q];                  \
        }                                                                    \
    }                                                                        \
    asm volatile("s_waitcnt lgkmcnt(0)" ::: "memory");                       \
    BARX();                                                                  \
    {   /* LSTM cell update (c in registers) */                              \
        f32x4 hv;                                                            \
        _Pragma("unroll")                                                    \
        for (int q = 0; q < 4; ++q) {                                        \
            float vi = Gb[0][bl][j0l+q] + bi[q];                             \
            float vf = Gb[1][bl][j0l+q] + bf[q];                             \
            float vg = Gb[2][bl][j0l+q] + bgi[q];                            \
            float vo = Gb[3][bl][j0l+q] + bo[q];                             \
            vi = 1.f / (1.f + __expf(-vi));                                  \
            vf = 1.f / (1.f + __expf(-vf));                                  \
            vg = 1.f - 2.f / (__expf(2.f * vg) + 1.f);  /* tanh, sat-safe */ \
            vo = 1.f / (1.f + __expf(-vo));                                  \
            const float cc = vf * cv[q] + vi * vg;                           \
            cv[q] = cc;                                                      \
            hv[q] = vo * (1.f - 2.f / (__expf(2.f * cc) + 1.f));             \
        }                                                                    \
        union { unsigned long long u; f16x4 v; } hu;                         \
        hu.v[0]=(_Float16)hv[0]; hu.v[1]=(_Float16)hv[1];                    \
        hu.v[2]=(_Float16)hv[2]; hu.v[3]=(_Float16)hv[3];                    \
        _Float16* hbw = hb + (size_t)(((P)+1)&1) * BATCH * HDIM;             \
        __hip_atomic_store((unsigned long long*)(hbw + (size_t)bg*HDIM + jg),\
                           hu.u, __ATOMIC_RELAXED, __HIP_MEMORY_SCOPE_AGENT);\
        if ((TT) == SEQ-1) *(f32x4*)(h32 + (size_t)bg*HDIM + jg) = hv;       \
    }                                                                        \
    asm volatile("s_waitcnt vmcnt(0)" ::: "memory");                         \
    BARX();                                                                  \
    if (tid == 0)                                                            \
        __hip_atomic_store(&cnt[bx*32+by], (TT)+1, __ATOMIC_RELAXED,         \
                           __HIP_MEMORY_SCOPE_AGENT);                        \
} while (0)

    // ---- prologue: stage step-0 chunks 0..3, write chunk 0 ----
    {
        const _Float16* xrow0 = xall + (size_t)b0 * KIH;
        const _Float16* xrow1 = xrow0 + (size_t)BATCH * KIH;   // unused here
        const _Float16* hrow0 = hb;                            // unused here
        (void)xrow1; (void)hrow0;
        LOADC(0, 0); LOADC(1, 0); LOADC(2, 0); LOADC(3, 0);
        char* _w = (char*)&ring[0][0][0];
        #pragma unroll
        for (int ii = 0; ii < 2; ++ii)
            *(f16x8*)(_w + woff[ii]) = rb[0][ii];
        asm volatile("s_waitcnt lgkmcnt(0)" ::: "memory");
        BARX();
    }

    for (int tb = 0; tb < SEQ; tb += 4) {
        STEP(tb + 0, 0);
        STEP(tb + 1, 1);
        STEP(tb + 2, 2);
        STEP(tb + 3, 3);
    }
#undef BARX
#undef LOADC
#undef ITER
#undef STEP
}

// ===========================================================================
// FALLBACK PATH (round-2, known-good) kernels
// ===========================================================================
__global__ __launch_bounds__(256) void prep_kernel(
    const float* __restrict__ Wih, const float* __restrict__ Whh,
    const float* __restrict__ bih, const float* __restrict__ bhh,
    _Float16* __restrict__ Wihc, _Float16* __restrict__ Whhc,
    float* __restrict__ bsum)
{
    const int g = blockIdx.x;
    for (int col = threadIdx.x; col < KIH; col += 256)
        Wihc[(size_t)g * KIH + col] =
            (col < INDIM) ? (_Float16)Wih[(size_t)g * INDIM + col] : (_Float16)0.f;
    for (int col = threadIdx.x; col < HDIM; col += 256)
        Whhc[(size_t)g * HDIM + col] = (_Float16)Whh[(size_t)g * HDIM + col];
    if (threadIdx.x == 0) bsum[g] = bih[g] + bhh[g];
}

__global__ __launch_bounds__(256) void fused_step_kernel(
    const float* __restrict__ xt, const _Float16* __restrict__ Wihc,
    const _Float16* __restrict__ Whhc, const float* __restrict__ bsum,
    float* __restrict__ c, float* __restrict__ h)
{
    __shared__ _Float16 As[32][72];
    __shared__ _Float16 Bs[128][72];
    __shared__ float    Gb[4][32][36];

    const int tid = threadIdx.x;
    const int b0  = blockIdx.x * 32;
    const int hc0 = blockIdx.y * 32;
    const int wid  = tid >> 6;
    const int lane = tid & 63;

    f32x4 acc[2][2] = {};
    const int arow = tid >> 3;
    const int ac8  = (tid & 7) * 8;
    const int brr  = tid >> 1;
    const int bseg = (tid & 1) * 32;

    for (int phase = 0; phase < 2; ++phase) {
        const float* Asrc = phase ? h : xt;
        const _Float16* Bsrc = phase ? Whhc : Wihc;
        const int Kpad = phase ? HDIM : KIH;
        const int Kval = phase ? HDIM : INDIM;
        const int astr = phase ? HDIM : INDIM;

        for (int k0 = 0; k0 < Kpad; k0 += 64) {
            const int gk = k0 + ac8;
            const float* pa = Asrc + (size_t)(b0 + arow) * astr + gk;
            float4 u = {0.f,0.f,0.f,0.f}, v = {0.f,0.f,0.f,0.f};
            if (gk + 3 < Kval)  u = *(const float4*)pa;
            if (gk + 7 < Kval)  v = *(const float4*)(pa + 4);
            f16x8 a8;
            a8[0]=(_Float16)u.x; a8[1]=(_Float16)u.y; a8[2]=(_Float16)u.z; a8[3]=(_Float16)u.w;
            a8[4]=(_Float16)v.x; a8[5]=(_Float16)v.y; a8[6]=(_Float16)v.z; a8[7]=(_Float16)v.w;
            const int grow = (brr >> 5) * HDIM + hc0 + (brr & 31);
            const _Float16* pb = Bsrc + (size_t)grow * Kpad + k0 + bseg;
            f16x8 w0 = *(const f16x8*)(pb + 0);
            f16x8 w1 = *(const f16x8*)(pb + 8);
            f16x8 w2 = *(const f16x8*)(pb + 16);
            f16x8 w3 = *(const f16x8*)(pb + 24);
            __syncthreads();
            *(f16x8*)&As[arow][ac8] = a8;
            *(f16x8*)&Bs[brr][bseg + 0]  = w0;
            *(f16x8*)&Bs[brr][bseg + 8]  = w1;
            *(f16x8*)&Bs[brr][bseg + 16] = w2;
            *(f16x8*)&Bs[brr][bseg + 24] = w3;
            __syncthreads();
            const int lr = lane & 15;
            const int lk = (lane >> 4) * 8;
            #pragma unroll
            for (int kf = 0; kf < 2; ++kf) {
                const int kl = kf * 32 + lk;
                f16x8 a0 = *(const f16x8*)&As[lr][kl];
                f16x8 a1 = *(const f16x8*)&As[16 + lr][kl];
                f16x8 bb0 = *(const f16x8*)&Bs[wid * 32 + lr][kl];
                f16x8 bb1 = *(const f16x8*)&Bs[wid * 32 + 16 + lr][kl];
                acc[0][0] = __builtin_amdgcn_mfma_f32_16x16x32_f16(a0, bb0, acc[0][0], 0, 0, 0);
                acc[0][1] = __builtin_amdgcn_mfma_f32_16x16x32_f16(a0, bb1, acc[0][1], 0, 0, 0);
                acc[1][0] = __builtin_amdgcn_mfma_f32_16x16x32_f16(a1, bb0, acc[1][0], 0, 0, 0);
                acc[1][1] = __builtin_amdgcn_mfma_f32_16x16x32_f16(a1, bb1, acc[1][1], 0, 0, 0);
            }
        }
    }
    __syncthreads();
    {
        const int cn = lane & 15;
        const int rbq = (lane >> 4) * 4;
        #pragma unroll
        for (int mi = 0; mi < 2; ++mi)
            #pragma unroll
            for (int ni = 0; ni < 2; ++ni)
                #pragma unroll
                for (int r = 0; r < 4; ++r)
                    Gb[wid][mi * 16 + rbq + r][ni * 16 + cn] = acc[mi][ni][r];
    }
    __syncthreads();
    {
        const int bl  = tid >> 3;
        const int jl0 = (tid & 7) * 4;
        const int gb  = b0 + bl;
        const int gj  = hc0 + jl0;
        const f32x4 ig = *(const f32x4*)&Gb[0][bl][jl0];
        const f32x4 fg = *(const f32x4*)&Gb[1][bl][jl0];
        const f32x4 gg = *(const f32x4*)&Gb[2][bl][jl0];
        const f32x4 og = *(const f32x4*)&Gb[3][bl][jl0];
        const f32x4 bi = *(const f32x4*)&bsum[0 * HDIM + gj];
        const f32x4 bf = *(const f32x4*)&bsum[1 * HDIM + gj];
        const f32x4 bg = *(const f32x4*)&bsum[2 * HDIM + gj];
        const f32x4 bo = *(const f32x4*)&bsum[3 * HDIM + gj];
        float* cp = c + (size_t)gb * HDIM + gj;
        float* hp = h + (size_t)gb * HDIM + gj;
        f32x4 cvv = *(const f32x4*)cp;
        f32x4 hv;
        #pragma unroll
        for (int q = 0; q < 4; ++q) {
            const float iv = 1.f / (1.f + __expf(-(ig[q] + bi[q])));
            const float fv = 1.f / (1.f + __expf(-(fg[q] + bf[q])));
            const float gv = tanhf(gg[q] + bg[q]);
            const float ov = 1.f / (1.f + __expf(-(og[q] + bo[q])));
            const float cc = fv * cvv[q] + iv * gv;
            cvv[q] = cc;
            hv[q] = ov * tanhf(cc);
        }
        *(f32x4*)cp = cvv;
        *(f32x4*)hp = hv;
    }
}

// ===========================================================================
// Shared epilogue
// ===========================================================================
__global__ __launch_bounds__(256) void bn_stats_kernel(
    const float* __restrict__ X, int nfeat,
    const float* __restrict__ gamma, const float* __restrict__ beta,
    float* __restrict__ s, float* __restrict__ t)
{
    const int f = blockIdx.x * 256 + threadIdx.x;
    if (f >= nfeat) return;
    float sum = 0.f, sq = 0.f;
    for (int b = 0; b < BATCH; ++b) {
        const float v = X[(size_t)b * nfeat + f];
        sum += v; sq += v * v;
    }
    const float mean = sum * (1.f / BATCH);
    const float var  = sq * (1.f / BATCH) - mean * mean;
    const float rstd = rsqrtf(var + 1e-5f);
    const float sc   = gamma[f] * rstd;
    s[f] = sc;
    t[f] = beta[f] - mean * sc;
}

__global__ __launch_bounds__(256) void fc1_kernel(
    const float* __restrict__ h, const float* __restrict__ s1,
    const float* __restrict__ t1, const float* __restrict__ W1,
    const float* __restrict__ b1, float* __restrict__ out1)
{
    const int b = blockIdx.x;
    const int l = threadIdx.x;
    const float* hbp = h  + (size_t)b * HDIM;
    const float* wl  = W1 + (size_t)l * HDIM;
    float acc = 0.f;
    for (int k = 0; k < HDIM; ++k)
        acc += (hbp[k] * s1[k] + t1[k]) * wl[k];
    out1[(size_t)b * LDIM + l] = acc + b1[l];
}

__global__ __launch_bounds__(256) void final_kernel(
    const float* __restrict__ out1, const float* __restrict__ s2,
    const float* __restrict__ t2, const float* __restrict__ W2,
    const float* __restrict__ b2, float* __restrict__ out)
{
    const int b = blockIdx.x;
    float v = out1[(size_t)b * LDIM + threadIdx.x];
    v = v * s2[threadIdx.x] + t2[threadIdx.x];
    v = fmaxf(v, 0.f);
    v *= W2[threadIdx.x];
    #pragma unroll
    for (int off = 32; off > 0; off >>= 1) v += __shfl_down(v, off);
    __shared__ float red[4];
    if ((threadIdx.x & 63) == 0) red[threadIdx.x >> 6] = v;
    __syncthreads();
    if (threadIdx.x == 0) {
        const float ssum = red[0] + red[1] + red[2] + red[3] + b2[0];
        out[b] = 4.f / (1.f + expf(-ssum));
    }
}

// ===========================================================================
extern "C" void kernel_launch(void* const* d_in, const int* in_sizes, int n_in,
                              void* d_out, int out_size, void* d_ws, size_t ws_size,
                              hipStream_t stream) {
    const float* x   = (const float*)d_in[0];
    const float* Wih = (const float*)d_in[1];
    const float* Whh = (const float*)d_in[2];
    const float* bih = (const float*)d_in[3];
    const float* bhh = (const float*)d_in[4];
    const float* g1  = (const float*)d_in[5];
    const float* be1 = (const float*)d_in[6];
    const float* W1  = (const float*)d_in[7];
    const float* b1  = (const float*)d_in[8];
    const float* g2  = (const float*)d_in[9];
    const float* be2 = (const float*)d_in[10];
    const float* W2  = (const float*)d_in[11];
    const float* b2  = (const float*)d_in[12];
    float* out = (float*)d_out;

    // ---- fast-path workspace layout ----
    const size_t SZ_XALL = (size_t)SEQ * BATCH * KIH * 2;       // 83,886,080
    const size_t SZ_SLAB = (size_t)32 * 64 * 832 * 2;           //  3,407,872
    const size_t SZ_HB   = (size_t)2 * BATCH * HDIM * 2;        //  1,048,576
    const size_t SZ_H32  = (size_t)BATCH * HDIM * 4;            //  1,048,576
    const size_t SZ_BSUM = (size_t)G4 * 4;
    const size_t SZ_CNT  = (size_t)SEQ * 8 * 4;
    const size_t SZ_ST   = (size_t)(HDIM * 2 + LDIM * 2) * 4;
    const size_t SZ_OUT1 = (size_t)BATCH * LDIM * 4;
    const size_t NEED = SZ_XALL + SZ_SLAB + SZ_HB + SZ_H32 + SZ_BSUM +
                        SZ_CNT + SZ_ST + SZ_OUT1;

    if (ws_size >= NEED) {
        char* p = (char*)d_ws;
        _Float16* xall = (_Float16*)p;           p += SZ_XALL;
        _Float16* slab = (_Float16*)p;           p += SZ_SLAB;
        _Float16* hbuf = (_Float16*)p;           p += SZ_HB;
        float* h32     = (float*)p;              p += SZ_H32;
        float* bsum    = (float*)p;              p += SZ_BSUM;
        int*   cnt     = (int*)p;                p += SZ_CNT;
        float* s1 = (float*)p;                   p += HDIM * 4;
        float* t1 = (float*)p;                   p += HDIM * 4;
        float* s2 = (float*)p;                   p += LDIM * 4;
        float* t2 = (float*)p;                   p += LDIM * 4;
        float* out1 = (float*)p;

        hipMemsetAsync(hbuf, 0, SZ_HB, stream);
        hipMemsetAsync(cnt, 0, SZ_CNT, stream);
        prep_weights_kernel<<<2048, 256, 0, stream>>>(Wih, Whh, bih, bhh, slab, bsum);
        prep_x_kernel<<<SEQ * 128, 256, 0, stream>>>(x, xall);

        // PLAIN launch: 256 blocks on 256 CUs (1 block/CU), co-resident by
        // construction; cross-block sync via per-block flags + relaxed polls.
        lstm_persist<<<dim3(256), dim3(256), 0, stream>>>(
            xall, slab, hbuf, h32, bsum, cnt);

        bn_stats_kernel<<<2, 256, 0, stream>>>(h32, HDIM, g1, be1, s1, t1);
        fc1_kernel<<<BATCH, 256, 0, stream>>>(h32, s1, t1, W1, b1, out1);
        bn_stats_kernel<<<1, 256, 0, stream>>>(out1, LDIM, g2, be2, s2, t2);
        final_kernel<<<BATCH, 256, 0, stream>>>(out1, s2, t2, W2, b2, out);
    } else {
        // ---- fallback: round-2 path ----
        float* ws   = (float*)d_ws;
        float* h    = ws;
        float* c    = h + BATCH * HDIM;
        float* bsum = c + BATCH * HDIM;
        float* s1   = bsum + G4;
        float* t1   = s1 + HDIM;
        float* s2   = t1 + HDIM;
        float* t2   = s2 + LDIM;
        float* out1 = t2 + LDIM;
        _Float16* Wihc = (_Float16*)(out1 + (size_t)BATCH * LDIM);
        _Float16* Whhc = Wihc + (size_t)G4 * KIH;

        hipMemsetAsync(h, 0, (size_t)2 * BATCH * HDIM * sizeof(float), stream);
        prep_kernel<<<G4, 256, 0, stream>>>(Wih, Whh, bih, bhh, Wihc, Whhc, bsum);
        const dim3 sgrid(BATCH / 32, HDIM / 32);
        for (int t = 0; t < SEQ; ++t) {
            fused_step_kernel<<<sgrid, 256, 0, stream>>>(
                x + (size_t)t * BATCH * INDIM, Wihc, Whhc, bsum, c, h);
        }
        bn_stats_kernel<<<2, 256, 0, stream>>>(h, HDIM, g1, be1, s1, t1);
        fc1_kernel<<<BATCH, 256, 0, stream>>>(h, s1, t1, W1, b1, out1);
        bn_stats_kernel<<<1, 256, 0, stream>>>(out1, LDIM, g2, be2, s2, t2);
        final_kernel<<<BATCH, 256, 0, stream>>>(out1, s2, t2, W2, b2, out);
    }
}